// Round 2
// baseline (164.454 us; speedup 1.0000x reference)
//
#include <hip/hip_runtime.h>

// PhraseAveragePretrainedEmbedding — fused prefix-sum formulation.
// out[b,t,:] = mean over contiguous span of W[leaves[b,r],:]
//   span = [lo, hi]   (or [hi+1, lo-1] if hi < lo, per the XOR-mask semantics)
// => out = (P[e] - P[a]) / max(e-a, 1) with per-batch prefix table P.
//
// 3 stream nodes:
//   0. hipMemsetAsync: zero lookback flags (ws is poisoned 0xAA each call)
//   1. build_P: grid (b,chunk)=8x32=256 blocks. Each block:
//        - re-does its batch's leaf compaction in LDS (redundant, cheap, L2-hot)
//        - computes 64-row chunk aggregate (values cached in 64 VGPRs)
//        - publishes aggregate (device-scope release + flag)
//        - polls ALL predecessor flags in parallel (thread i polls flag i;
//          no serial chain; grid=256 <= #CUs so all blocks co-resident)
//        - base = sum of predecessor aggregates; writes its 64 P rows
//   2. out_kernel: out = (P[e]-P[a]) * inv_cnt

#define BB 8
#define TT 4095
#define SS 2048
#define DD 300
#define PADIDX 1
#define CHUNK 64
#define NC (SS / CHUNK)  // 32
#define NT 320           // 5 waves

__global__ __launch_bounds__(NT, 1) void build_P(const int* __restrict__ x,
                                                 const int* __restrict__ idx,
                                                 const float* __restrict__ W,
                                                 float* __restrict__ csum,
                                                 int* __restrict__ flags,
                                                 float* __restrict__ P) {
    int blk = blockIdx.x;
    int b = blk / NC, c = blk - b * NC;
    int tid = threadIdx.x;
    int lane = tid & 63, w = tid >> 6;  // 5 waves

    __shared__ int sx[TT];        // 16380 B
    __shared__ int sidx[2 * TT];  // 32760 B
    __shared__ int lf[SS];        // 8192 B
    __shared__ int wcnt[5];
    __shared__ int sbase;

    // ---- load batch x/idx into LDS (coalesced) ----
    const int* xb = x + b * TT;
    const int* ib = idx + b * 2 * TT;
    for (int i = tid; i < TT; i += NT) sx[i] = xb[i];
    for (int i = tid; i < 2 * TT; i += NT) sidx[i] = ib[i];
    if (tid == 0) sbase = 0;
    __syncthreads();

    // ---- leaf compaction (ballot scan over 5 waves) ----
    for (int t0 = 0; t0 < TT; t0 += NT) {
        int t = t0 + tid;
        bool leaf = false;
        int xv = 0;
        if (t < TT) {
            xv = sx[t];
            leaf = (sidx[2 * t] == sidx[2 * t + 1]) && (xv != PADIDX);
        }
        unsigned long long bal = __ballot(leaf);
        if (lane == 0) wcnt[w] = __popcll(bal);
        __syncthreads();
        int off = sbase;
        for (int i = 0; i < w; ++i) off += wcnt[i];
        int pos = off + __popcll(bal & ((1ull << lane) - 1ull));
        if (leaf && pos < SS) lf[pos] = xv;
        __syncthreads();
        if (tid == 0) sbase += wcnt[0] + wcnt[1] + wcnt[2] + wcnt[3] + wcnt[4];
        __syncthreads();
    }
    for (int i = sbase + tid; i < SS; i += NT) lf[i] = PADIDX;
    __syncthreads();

    // ---- phase A: chunk aggregate, values kept in registers ----
    int d = tid;
    float wv[CHUNK];
    float agg = 0.f;
    int s0 = c * CHUNK;
    if (d < DD) {
#pragma unroll
        for (int i = 0; i < CHUNK; ++i) {
            int row = lf[s0 + i];
            wv[i] = W[row * DD + d];
            agg += wv[i];
        }
        __hip_atomic_store(&csum[(b * NC + c) * DD + d], agg,
                           __ATOMIC_RELAXED, __HIP_MEMORY_SCOPE_AGENT);
    }
    __threadfence();
    __syncthreads();
    if (tid == 0)
        __hip_atomic_store(&flags[b * NC + c], 1,
                           __ATOMIC_RELEASE, __HIP_MEMORY_SCOPE_AGENT);

    // ---- phase B: parallel wait for all predecessors, sum their aggregates ----
    if (tid < c) {
        while (__hip_atomic_load(&flags[b * NC + tid],
                                 __ATOMIC_ACQUIRE, __HIP_MEMORY_SCOPE_AGENT) == 0)
            __builtin_amdgcn_s_sleep(2);
    }
    __syncthreads();

    float basev = 0.f;
    if (d < DD) {
#pragma unroll 4
        for (int cc = 0; cc < c; ++cc)
            basev += __hip_atomic_load(&csum[(b * NC + cc) * DD + d],
                                       __ATOMIC_RELAXED, __HIP_MEMORY_SCOPE_AGENT);

        // ---- phase C: write P rows for this chunk ----
        float* Pb = P + (size_t)b * (SS + 1) * DD;
        float run = basev;
#pragma unroll
        for (int i = 0; i < CHUNK; ++i) {
            Pb[(s0 + i) * DD + d] = run;
            run += wv[i];
        }
        if (c == NC - 1) Pb[SS * DD + d] = run;
    }
}

__global__ __launch_bounds__(NT) void out_kernel(const int* __restrict__ idx,
                                                 const float* __restrict__ P,
                                                 float* __restrict__ out) {
    int bt = blockIdx.x;
    int b = bt / TT;
    int lo = idx[bt * 2], hi = idx[bt * 2 + 1];
    int u = hi + 1;
    int a = min(lo, u), e = max(lo, u);
    a = max(0, min(a, SS));
    e = max(0, min(e, SS));
    int cnt = e - a;
    float inv = 1.0f / (float)(cnt > 0 ? cnt : 1);
    int d = threadIdx.x;
    if (d >= DD) return;
    const float* Pb = P + (size_t)b * (SS + 1) * DD;
    out[bt * DD + d] = (Pb[e * DD + d] - Pb[a * DD + d]) * inv;
}

extern "C" void kernel_launch(void* const* d_in, const int* in_sizes, int n_in,
                              void* d_out, int out_size, void* d_ws, size_t ws_size,
                              hipStream_t stream) {
    const int* x = (const int*)d_in[0];
    const int* idx = (const int*)d_in[1];
    const float* W = (const float*)d_in[2];
    float* out = (float*)d_out;

    char* ws = (char*)d_ws;
    int* flags = (int*)ws;                     // 256 ints (1 KiB reserved)
    float* csum = (float*)(ws + 1024);         // B*NC*DD floats = 307200 B
    float* P = (float*)(ws + 1024 + 307200);   // B*(SS+1)*DD floats = 18.8 MiB

    hipMemsetAsync(flags, 0, BB * NC * sizeof(int), stream);
    build_P<<<BB * NC, NT, 0, stream>>>(x, idx, W, csum, flags, P);
    out_kernel<<<BB * TT, NT, 0, stream>>>(idx, P, out);
}

// Round 3
// 154.537 us; speedup vs baseline: 1.0642x; 1.0642x over previous
//
#include <hip/hip_runtime.h>

// PhraseAveragePretrainedEmbedding — prefix-sum formulation, v3.
// out[b,t,:] = (P[e]-P[a]) / max(e-a,1), spans contiguous by the XOR-mask identity.
//
// 4 stream nodes:
//   0. memset flags (ws is poisoned 0xAA)
//   1. leaves_kernel: per-batch ballot stream-compaction (8 blocks x 512)
//   2. build_P: 256 blocks (b,chunk). Chunk of 64 gathered W rows staged in
//      LDS (76.8 KB) to avoid the R2 register spill; decoupled lookback via
//      per-chunk aggregates + flags (all-predecessor parallel poll).
//   3. out_kernel: 2048 blocks x 320, 16 rows/block, float4 (300 = 75*4).

#define BB 8
#define TT 4095
#define SS 2048
#define DD 300
#define PADIDX 1
#define CHUNK 64
#define NC (SS / CHUNK)  // 32
#define NTB 320

__global__ __launch_bounds__(512) void leaves_kernel(const int* __restrict__ x,
                                                     const int* __restrict__ idx,
                                                     int* __restrict__ leaves) {
    int b = blockIdx.x, tid = threadIdx.x;
    int lane = tid & 63, w = tid >> 6;  // 8 waves
    __shared__ int wcnt[8];
    __shared__ int sbase;
    if (tid == 0) sbase = 0;
    __syncthreads();
    const int* xb = x + b * TT;
    const int* ib = idx + b * 2 * TT;
    for (int t0 = 0; t0 < TT; t0 += 512) {
        int t = t0 + tid;
        bool leaf = false;
        int xv = 0;
        if (t < TT) {
            xv = xb[t];
            leaf = (ib[2 * t] == ib[2 * t + 1]) && (xv != PADIDX);
        }
        unsigned long long bal = __ballot(leaf);
        if (lane == 0) wcnt[w] = __popcll(bal);
        __syncthreads();
        int off = sbase;
        for (int i = 0; i < w; ++i) off += wcnt[i];
        int pos = off + __popcll(bal & ((1ull << lane) - 1ull));
        if (leaf && pos < SS) leaves[b * SS + pos] = xv;
        __syncthreads();
        if (tid == 0) {
            int s = 0;
            for (int i = 0; i < 8; ++i) s += wcnt[i];
            sbase += s;
        }
        __syncthreads();
    }
    for (int i = sbase + tid; i < SS; i += 512) leaves[b * SS + i] = PADIDX;
}

__global__ __launch_bounds__(NTB, 1) void build_P(const int* __restrict__ leaves,
                                                  const float* __restrict__ W,
                                                  float* __restrict__ csum,
                                                  int* __restrict__ flags,
                                                  float* __restrict__ P) {
    int blk = blockIdx.x;
    int b = blk >> 5, c = blk & (NC - 1);
    int tid = threadIdx.x;

    __shared__ int lf[CHUNK];
    __shared__ float sw[CHUNK * DD];  // 76800 B — gathered W rows for this chunk

    if (tid < CHUNK) lf[tid] = leaves[b * SS + c * CHUNK + tid];
    __syncthreads();

    int d = tid;
    float agg = 0.f;
    if (d < DD) {
#pragma unroll 8
        for (int i = 0; i < CHUNK; ++i) {
            float v = W[lf[i] * DD + d];
            sw[i * DD + d] = v;
            agg += v;
        }
        __hip_atomic_store(&csum[(b * NC + c) * DD + d], agg,
                           __ATOMIC_RELAXED, __HIP_MEMORY_SCOPE_AGENT);
    }
    __threadfence();
    __syncthreads();
    if (tid == 0)
        __hip_atomic_store(&flags[blk], 1,
                           __ATOMIC_RELEASE, __HIP_MEMORY_SCOPE_AGENT);

    // parallel all-predecessor wait (thread i polls predecessor i; c <= 31 < NTB)
    if (tid < c) {
        while (__hip_atomic_load(&flags[b * NC + tid],
                                 __ATOMIC_ACQUIRE, __HIP_MEMORY_SCOPE_AGENT) == 0)
            __builtin_amdgcn_s_sleep(1);
    }
    __syncthreads();

    if (d < DD) {
        float run = 0.f;
#pragma unroll 4
        for (int cc = 0; cc < c; ++cc)
            run += csum[(b * NC + cc) * DD + d];

        float* Pb = P + (size_t)b * (SS + 1) * DD;
        int s0 = c * CHUNK;
#pragma unroll 4
        for (int i = 0; i < CHUNK; ++i) {
            Pb[(s0 + i) * DD + d] = run;
            run += sw[i * DD + d];
        }
        if (c == NC - 1) Pb[SS * DD + d] = run;
    }
}

// 320 threads = 4 rows x 80 lanes (75 active float4 lanes per row); 16 rows/block
__global__ __launch_bounds__(NTB) void out_kernel(const int* __restrict__ idx,
                                                  const float* __restrict__ P,
                                                  float* __restrict__ out) {
    int tid = threadIdx.x;
    int r = tid / 80, j = tid - r * 80;
    int base_bt = blockIdx.x * 16 + r;
    const float4* P4 = (const float4*)P;
    float4* out4 = (float4*)out;
#pragma unroll
    for (int it = 0; it < 4; ++it) {
        int bt = base_bt + it * 4;
        if (bt >= BB * TT || j >= 75) continue;
        int b = bt / TT;
        int lo = idx[2 * bt], hi = idx[2 * bt + 1];
        int u = hi + 1;
        int a = min(lo, u), e = max(lo, u);
        a = max(0, min(a, SS));
        e = max(0, min(e, SS));
        int cnt = e - a;
        float inv = 1.0f / (float)(cnt > 0 ? cnt : 1);
        size_t pb = (size_t)b * (SS + 1);
        float4 ve = P4[(pb + e) * 75 + j];
        float4 va = P4[(pb + a) * 75 + j];
        float4 o;
        o.x = (ve.x - va.x) * inv;
        o.y = (ve.y - va.y) * inv;
        o.z = (ve.z - va.z) * inv;
        o.w = (ve.w - va.w) * inv;
        out4[(size_t)bt * 75 + j] = o;
    }
}

extern "C" void kernel_launch(void* const* d_in, const int* in_sizes, int n_in,
                              void* d_out, int out_size, void* d_ws, size_t ws_size,
                              hipStream_t stream) {
    const int* x = (const int*)d_in[0];
    const int* idx = (const int*)d_in[1];
    const float* W = (const float*)d_in[2];
    float* out = (float*)d_out;

    char* ws = (char*)d_ws;
    int* flags = (int*)ws;                       // 256 ints (4 KiB reserved)
    int* leaves = (int*)(ws + 4096);             // B*SS ints = 64 KiB
    float* csum = (float*)(ws + 4096 + 65536);   // B*NC*DD floats = 300 KiB
    float* P = (float*)(ws + 4096 + 65536 + 307200);  // B*(SS+1)*DD = 18.8 MiB (16B aligned)

    hipMemsetAsync(flags, 0, BB * NC * sizeof(int), stream);
    leaves_kernel<<<BB, 512, 0, stream>>>(x, idx, leaves);
    build_P<<<BB * NC, NTB, 0, stream>>>(leaves, W, csum, flags, P);
    out_kernel<<<(BB * TT + 15) / 16, NTB, 0, stream>>>(idx, P, out);
}

// Round 4
// 123.338 us; speedup vs baseline: 1.3334x; 1.2530x over previous
//
#include <hip/hip_runtime.h>

// PhraseAveragePretrainedEmbedding — prefix-sum formulation, v4.
// out[b,t,:] = (P[e]-P[a]) / max(e-a,1); spans are contiguous by the
// XOR-mask identity (a=min(lo,hi+1), e=max(lo,hi+1)).
//
// v3 post-mortem: monolithic lookback kernel was latency-bound (50 µs,
// VALUBusy 2%, occupancy 11.5%): 1 block/CU (77 KB LDS), sc1 atomics
// bypassing L2, threadfence drain, all blocks idling on slowest gather.
// v4: kernel boundaries ARE the sync — no atomics/fences/flags.
//
//   1. leaves_kernel: per-batch ballot stream-compaction (8 x 512)
//   2. csum_kernel : per-(b,chunk) 32-row chunk sums. 512 blocks, 2/CU.
//   3. buildP_kernel: base = sum of predecessor chunk sums (L2-hot csum),
//                     re-gather 32 W rows (LLC-hot), write P rows.
//   4. out_kernel  : out = (P[e]-P[a]) * inv, float4 (300 = 75*4).

#define BB 8
#define TT 4095
#define SS 2048
#define DD 300
#define PADIDX 1
#define CHUNK 32
#define NC (SS / CHUNK)  // 64
#define NTB 320

__global__ __launch_bounds__(512) void leaves_kernel(const int* __restrict__ x,
                                                     const int* __restrict__ idx,
                                                     int* __restrict__ leaves) {
    int b = blockIdx.x, tid = threadIdx.x;
    int lane = tid & 63, w = tid >> 6;  // 8 waves
    __shared__ int wcnt[8];
    __shared__ int sbase;
    if (tid == 0) sbase = 0;
    __syncthreads();
    const int* xb = x + b * TT;
    const int* ib = idx + b * 2 * TT;
    for (int t0 = 0; t0 < TT; t0 += 512) {
        int t = t0 + tid;
        bool leaf = false;
        int xv = 0;
        if (t < TT) {
            xv = xb[t];
            leaf = (ib[2 * t] == ib[2 * t + 1]) && (xv != PADIDX);
        }
        unsigned long long bal = __ballot(leaf);
        if (lane == 0) wcnt[w] = __popcll(bal);
        __syncthreads();
        int off = sbase;
        for (int i = 0; i < w; ++i) off += wcnt[i];
        int pos = off + __popcll(bal & ((1ull << lane) - 1ull));
        if (leaf && pos < SS) leaves[b * SS + pos] = xv;
        __syncthreads();
        if (tid == 0) {
            int s = 0;
            for (int i = 0; i < 8; ++i) s += wcnt[i];
            sbase += s;
        }
        __syncthreads();
    }
    for (int i = sbase + tid; i < SS; i += 512) leaves[b * SS + i] = PADIDX;
}

__global__ __launch_bounds__(NTB) void csum_kernel(const int* __restrict__ leaves,
                                                   const float* __restrict__ W,
                                                   float* __restrict__ csum) {
    int blk = blockIdx.x;
    int b = blk >> 6, c = blk & (NC - 1);
    int tid = threadIdx.x;
    __shared__ int lf[CHUNK];
    if (tid < CHUNK) lf[tid] = leaves[b * SS + c * CHUNK + tid];
    __syncthreads();
    int d = tid;
    if (d >= DD) return;
    float acc = 0.f;
#pragma unroll 8
    for (int i = 0; i < CHUNK; ++i) acc += W[lf[i] * DD + d];
    csum[(b * NC + c) * DD + d] = acc;
}

__global__ __launch_bounds__(NTB) void buildP_kernel(const int* __restrict__ leaves,
                                                     const float* __restrict__ W,
                                                     const float* __restrict__ csum,
                                                     float* __restrict__ P) {
    int blk = blockIdx.x;
    int b = blk >> 6, c = blk & (NC - 1);
    int tid = threadIdx.x;
    __shared__ int lf[CHUNK];
    if (tid < CHUNK) lf[tid] = leaves[b * SS + c * CHUNK + tid];
    __syncthreads();
    int d = tid;
    if (d >= DD) return;

    // base = sum of predecessor chunk aggregates (csum is L2/LLC-hot, 600 KB)
    float base = 0.f;
#pragma unroll 4
    for (int cc = 0; cc < c; ++cc) base += csum[(b * NC + cc) * DD + d];

    // gather this chunk's W values into registers (independent loads)
    float v[CHUNK];
#pragma unroll
    for (int i = 0; i < CHUNK; ++i) v[i] = W[lf[i] * DD + d];

    float* Pb = P + (size_t)b * (SS + 1) * DD;
    int s0 = c * CHUNK;
    float run = base;
#pragma unroll
    for (int i = 0; i < CHUNK; ++i) {
        Pb[(s0 + i) * DD + d] = run;
        run += v[i];
    }
    if (c == NC - 1) Pb[SS * DD + d] = run;
}

// 320 threads = 4 row-groups x 80 lanes (75 active float4 lanes); 16 rows/block
__global__ __launch_bounds__(NTB) void out_kernel(const int* __restrict__ idx,
                                                  const float* __restrict__ P,
                                                  float* __restrict__ out) {
    int tid = threadIdx.x;
    int r = tid / 80, j = tid - r * 80;
    int base_bt = blockIdx.x * 16 + r;
    const float4* P4 = (const float4*)P;
    float4* out4 = (float4*)out;
#pragma unroll
    for (int it = 0; it < 4; ++it) {
        int bt = base_bt + it * 4;
        if (bt >= BB * TT || j >= 75) continue;
        int b = bt / TT;
        int lo = idx[2 * bt], hi = idx[2 * bt + 1];
        int u = hi + 1;
        int a = min(lo, u), e = max(lo, u);
        a = max(0, min(a, SS));
        e = max(0, min(e, SS));
        int cnt = e - a;
        float inv = 1.0f / (float)(cnt > 0 ? cnt : 1);
        size_t pb = (size_t)b * (SS + 1);
        float4 ve = P4[(pb + e) * 75 + j];
        float4 va = P4[(pb + a) * 75 + j];
        float4 o;
        o.x = (ve.x - va.x) * inv;
        o.y = (ve.y - va.y) * inv;
        o.z = (ve.z - va.z) * inv;
        o.w = (ve.w - va.w) * inv;
        out4[(size_t)bt * 75 + j] = o;
    }
}

extern "C" void kernel_launch(void* const* d_in, const int* in_sizes, int n_in,
                              void* d_out, int out_size, void* d_ws, size_t ws_size,
                              hipStream_t stream) {
    const int* x = (const int*)d_in[0];
    const int* idx = (const int*)d_in[1];
    const float* W = (const float*)d_in[2];
    float* out = (float*)d_out;

    char* ws = (char*)d_ws;
    int* leaves = (int*)ws;                         // B*SS ints   = 64 KiB
    float* csum = (float*)(ws + 65536);             // B*NC*DD f32 = 600 KiB
    float* P = (float*)(ws + 65536 + 614400);       // B*(SS+1)*DD = 18.8 MiB (16B-aligned)

    leaves_kernel<<<BB, 512, 0, stream>>>(x, idx, leaves);
    csum_kernel<<<BB * NC, NTB, 0, stream>>>(leaves, W, csum);
    buildP_kernel<<<BB * NC, NTB, 0, stream>>>(leaves, W, csum, P);
    out_kernel<<<(BB * TT + 15) / 16, NTB, 0, stream>>>(idx, P, out);
}